// Round 2
// baseline (885.519 us; speedup 1.0000x reference)
//
#include <hip/hip_runtime.h>

// GsumLayer: out[b] = a[b] @ x[b], B=8, N=4096, D=32, fp32.
// a (536 MB) has ZERO reuse -> stream it straight to registers (no LDS).
// x (512 KB/batch) has all the reuse -> LDS, broadcast ds_read per m.
// K-split x16 for occupancy; partials in d_ws; deterministic reduce pass.
//
// d_in[0] = x [B,N,D], d_in[1] = a [B,N,N].

#define N_ 4096
#define D_ 32
#define MSPLIT 16
#define MCHUNK (N_ / MSPLIT)        // 256 m per block
#define PART_ELEMS (8 * N_ * D_)    // 1048576 floats per split

// Block: 256 threads = 4 waves. Wave covers 64 rows x 32 cols:
//   lane: g = l&7 -> cols 4g..4g+3 ; r = (l>>3)&7 -> rows r*8..r*8+7 (i loop)
// Block covers 256 rows. Grid: (128 row-blocks, 16 m-splits).
__global__ __launch_bounds__(256, 4) void gsum_stage1(
    const float* __restrict__ x,
    const float* __restrict__ a,
    float* __restrict__ part)
{
    __shared__ float Xs[MCHUNK * D_];   // 256 x 32 floats = 32 KB

    const int t  = threadIdx.x;
    const int rb = blockIdx.x;          // 0..127
    const int ms = blockIdx.y;          // 0..15
    const int b  = rb >> 4;             // 16 row-blocks per batch
    const int n0 = (rb & 15) * 256;
    const int m0 = ms * MCHUNK;

    // ---- stage x chunk (contiguous 32 KB), fully coalesced, conflict-free
    {
        const float4* src = (const float4*)(x + ((long long)b * N_ + m0) * D_);
        float4* dst = (float4*)Xs;
        #pragma unroll
        for (int j = 0; j < 8; ++j)
            dst[t + j * 256] = src[t + j * 256];
    }
    __syncthreads();

    const int g   = t & 7;
    const int r   = (t >> 3) & 7;
    const int wid = t >> 6;
    const int row_base = n0 + wid * 64 + r * 8;   // this lane's 8 rows

    const float* ap = a + ((long long)(b * N_ + row_base)) * N_ + m0;

    float4 acc[8];
    #pragma unroll
    for (int i = 0; i < 8; ++i) acc[i] = make_float4(0.f, 0.f, 0.f, 0.f);

    // ---- barrier-free main loop: per 4 m: 8 a-float4 loads, 4 x ds_reads, 128 FMA
    for (int mm = 0; mm < MCHUNK; mm += 4) {
        float4 av[8];
        #pragma unroll
        for (int i = 0; i < 8; ++i)
            av[i] = *(const float4*)(ap + (long long)i * N_ + mm);
        #pragma unroll
        for (int j = 0; j < 4; ++j) {
            float4 xv = *(const float4*)&Xs[(mm + j) * D_ + g * 4];
            #pragma unroll
            for (int i = 0; i < 8; ++i) {
                float aj = (j == 0) ? av[i].x : (j == 1) ? av[i].y
                         : (j == 2) ? av[i].z : av[i].w;
                acc[i].x += aj * xv.x;
                acc[i].y += aj * xv.y;
                acc[i].z += aj * xv.z;
                acc[i].w += aj * xv.w;
            }
        }
    }

    // ---- write partials (every slot written, no init needed)
    float* op = part + (long long)ms * PART_ELEMS
                     + ((long long)(b * N_ + row_base)) * D_ + g * 4;
    #pragma unroll
    for (int i = 0; i < 8; ++i)
        *(float4*)(op + i * D_) = acc[i];
}

__global__ __launch_bounds__(256, 4) void gsum_reduce(
    const float* __restrict__ part,
    float* __restrict__ out)
{
    const int idx = blockIdx.x * 256 + threadIdx.x;   // float4 index, 262144 total
    const float4* p = (const float4*)part;
    float4 s = p[idx];
    #pragma unroll
    for (int sft = 1; sft < MSPLIT; ++sft) {
        float4 v = p[idx + (long long)sft * (PART_ELEMS / 4)];
        s.x += v.x; s.y += v.y; s.z += v.z; s.w += v.w;
    }
    ((float4*)out)[idx] = s;
}

extern "C" void kernel_launch(void* const* d_in, const int* in_sizes, int n_in,
                              void* d_out, int out_size, void* d_ws, size_t ws_size,
                              hipStream_t stream) {
    const float* x = (const float*)d_in[0];   // [B, N, D]
    const float* a = (const float*)d_in[1];   // [B, N, N]
    float* out  = (float*)d_out;              // [B, N, D]
    float* part = (float*)d_ws;               // 16 x 4 MB partials

    dim3 grid1(128, MSPLIT);                  // 2048 blocks
    gsum_stage1<<<grid1, 256, 0, stream>>>(x, a, part);

    dim3 grid2(PART_ELEMS * MSPLIT / 4 / 256 / MSPLIT);   // 1024 blocks
    gsum_reduce<<<grid2, 256, 0, stream>>>(part, out);
}